// Round 1
// baseline (1771.430 us; speedup 1.0000x reference)
//
#include <hip/hip_runtime.h>
#include <math.h>

#define LSLOPE 0.01f

__device__ __forceinline__ float lrelu(float x){ return x >= 0.f ? x : LSLOPE * x; }

constexpr int B    = 16;
constexpr int CIN  = 256;
constexpr int COUT = 256;
constexpr int HH   = 64;
constexpr int WW   = 64;
constexpr int KK   = 3;
constexpr int FD   = 128;
constexpr int LAT  = 128;
constexpr int WPS  = CIN * KK * KK;     // 2304 weights per (b, oc)
constexpr int WTOT = COUT * WPS;        // 589824 weights per sample
constexpr int NPART = 64;               // partial-reduction slots

// ---- workspace layout (in floats) ----
constexpr int OFF_STAT  = 0;            // [2]  mean_ori, std_ori
constexpr int OFF_BMEAN = 16;           // [16]
constexpr int OFF_BSTD  = 32;           // [16]
constexpr int OFF_OPS   = 64;           // [64]  ori partial sums
constexpr int OFF_OPQ   = 128;          // [64]  ori partial sumsq
constexpr int OFF_PS    = 192;          // [16*64] per-sample partial sums
constexpr int OFF_PQ    = 1216;         // [16*64]
constexpr int OFF_H     = 2240;         // [16*128]
constexpr int OFF_STYLE = 4288;         // [16*4608]
constexpr int OFF_NBIAS = 78016;        // [16*256]
constexpr int OFF_NW    = 82176;        // [16*589824]  materialized new_weight

// ---------- global weight stats (two-stage, deterministic) ----------
__global__ void k_ori_part(const float* __restrict__ ow, float* psum, float* psq){
  const int p = blockIdx.x;                 // 0..63
  const int chunk = WTOT / NPART;           // 9216
  const int base = p * chunk;
  float s = 0.f, q = 0.f;
  for (int i = threadIdx.x; i < chunk; i += 256){
    float v = ow[base + i];
    s += v; q += v * v;
  }
  __shared__ float ss[256], sq[256];
  ss[threadIdx.x] = s; sq[threadIdx.x] = q; __syncthreads();
  for (int st = 128; st > 0; st >>= 1){
    if (threadIdx.x < st){ ss[threadIdx.x] += ss[threadIdx.x + st]; sq[threadIdx.x] += sq[threadIdx.x + st]; }
    __syncthreads();
  }
  if (threadIdx.x == 0){ psum[p] = ss[0]; psq[p] = sq[0]; }
}

__global__ void k_ori_final(const float* __restrict__ psum, const float* __restrict__ psq, float* stat){
  int t = threadIdx.x;  // 64 threads
  float s = psum[t], q = psq[t];
  for (int o = 32; o > 0; o >>= 1){ s += __shfl_down(s, o); q += __shfl_down(q, o); }
  if (t == 0){
    const float N = (float)WTOT;
    stat[0] = s / N;
    stat[1] = sqrtf((q - s * s / N) / (N - 1.f));
  }
}

// ---------- style MLP ----------
__global__ void k_style_h(const float* __restrict__ finger, const float* __restrict__ sw1, float* __restrict__ h){
  int idx = blockIdx.x * blockDim.x + threadIdx.x;
  if (idx >= B * LAT) return;
  int b = idx / LAT, l = idx - b * LAT;
  float acc = 0.f;
  for (int f = 0; f < FD; ++f) acc += finger[b * FD + f] * sw1[l * FD + f];
  h[idx] = lrelu(acc);
}

__global__ void k_style(const float* __restrict__ h, const float* __restrict__ sw2, float* __restrict__ style){
  int idx = blockIdx.x * blockDim.x + threadIdx.x;
  if (idx >= B * 2 * WPS) return;
  int b = idx / (2 * WPS), j = idx - b * 2 * WPS;
  float acc = 0.f;
  for (int l = 0; l < LAT; ++l) acc += h[b * LAT + l] * sw2[j * LAT + l];
  style[idx] = acc;
}

// ---------- per-sample bias ----------
__global__ void k_bias(const float* __restrict__ finger, const float* __restrict__ bw1,
                       const float* __restrict__ bw2, const float* __restrict__ fbias,
                       const float* __restrict__ bmask, const float* __restrict__ obias,
                       float* __restrict__ nbias){
  __shared__ float hb[COUT];
  const int b = blockIdx.x, o = threadIdx.x;
  float acc = 0.f;
  for (int f = 0; f < FD; ++f) acc += finger[b * FD + f] * bw1[o * FD + f];
  hb[o] = lrelu(acc);
  __syncthreads();
  float t = 0.f;
  for (int c = 0; c < COUT; ++c) t += hb[c] * bw2[o * COUT + c];
  t = lrelu(t);
  float sb = fbias[o] * t;
  float fwb = (6.f - fminf(fmaxf(bmask[o], 0.f), 6.f)) * (1.f / 6.f);
  nbias[b * COUT + o] = (1.f - fwb) * obias[o] + fwb * sb;
}

// ---------- per-sample w1 stats (two-stage, deterministic) ----------
__global__ void k_w1_part(const float* __restrict__ ow, const float* __restrict__ fwgt,
                          const float* __restrict__ wmask, const float* __restrict__ style,
                          float* psum, float* psq){
  const int p = blockIdx.x, b = blockIdx.y;
  const float* st = style + b * 2 * WPS;
  const int chunk = WTOT / NPART;           // 9216
  const int base = p * chunk;
  float s = 0.f, q = 0.f;
  for (int ii = threadIdx.x; ii < chunk; ii += 256){
    int idx = base + ii;
    int o = idx / WPS; int rem = idx - o * WPS; int ci = rem / 9;
    float fw = (6.f - fminf(fmaxf(wmask[o * CIN + ci], 0.f), 6.f)) * (1.f / 6.f);
    float owv = ow[idx];
    float sw = fwgt[idx] * (st[rem] + 1.f) + st[WPS + rem];
    float w1 = owv + fw * (sw - owv);
    s += w1; q += w1 * w1;
  }
  __shared__ float ss[256], sq[256];
  ss[threadIdx.x] = s; sq[threadIdx.x] = q; __syncthreads();
  for (int st2 = 128; st2 > 0; st2 >>= 1){
    if (threadIdx.x < st2){ ss[threadIdx.x] += ss[threadIdx.x + st2]; sq[threadIdx.x] += sq[threadIdx.x + st2]; }
    __syncthreads();
  }
  if (threadIdx.x == 0){ psum[b * NPART + p] = ss[0]; psq[b * NPART + p] = sq[0]; }
}

__global__ void k_w1_final(const float* __restrict__ psum, const float* __restrict__ psq,
                           float* bmean, float* bstd){
  const int b = blockIdx.x;
  int t = threadIdx.x;  // 64 threads
  float s = psum[b * NPART + t], q = psq[b * NPART + t];
  for (int o = 32; o > 0; o >>= 1){ s += __shfl_down(s, o); q += __shfl_down(q, o); }
  if (t == 0){
    const float N = (float)WTOT;
    bmean[b] = s / N;
    bstd[b] = sqrtf((q - s * s / N) / (N - 1.f));
  }
}

// ---------- materialize new_weight ----------
__global__ void k_new_weight(const float* __restrict__ ow, const float* __restrict__ fwgt,
                             const float* __restrict__ wmask, const float* __restrict__ style,
                             const float* __restrict__ stat, const float* __restrict__ bmean,
                             const float* __restrict__ bstd, float* __restrict__ nw){
  const int total = B * WTOT;
  const float mean_ori = stat[0], std_ori = stat[1];
  for (int idx = blockIdx.x * blockDim.x + threadIdx.x; idx < total; idx += gridDim.x * blockDim.x){
    int b = idx / WTOT; int r = idx - b * WTOT;
    int o = r / WPS; int rem = r - o * WPS; int ci = rem / 9;
    const float* st = style + b * 2 * WPS;
    float fw = (6.f - fminf(fmaxf(wmask[o * CIN + ci], 0.f), 6.f)) * (1.f / 6.f);
    float owv = ow[r];
    float sw = fwgt[r] * (st[rem] + 1.f) + st[WPS + rem];
    float w1 = owv + fw * (sw - owv);
    float w2 = (w1 - bmean[b]) / bstd[b] * std_ori + mean_ori;
    nw[idx] = owv + fw * (w2 - owv);
  }
}

// ---------- per-sample 3x3 conv ----------
// grid: (4 w-tiles, 32 oc-tiles of 8, 16 samples); block 256.
// Each thread: w = w0+tx, h in {ty, ty+16, ty+32, ty+48}, 8 oc accumulators.
__global__ __launch_bounds__(256) void k_conv(const float* __restrict__ y,
                                              const float* __restrict__ nw,
                                              const float* __restrict__ nbias,
                                              float* __restrict__ out){
  __shared__ float yt[8 * 66 * 18];
  __shared__ float wt[8 * 8 * 9];
  const int w0 = blockIdx.x * 16;
  const int oc0 = blockIdx.y * 8;
  const int b = blockIdx.z;
  const int tid = threadIdx.x;
  const int tx = tid & 15, ty = tid >> 4;

  float acc[8][4];
  #pragma unroll
  for (int i = 0; i < 8; ++i)
    #pragma unroll
    for (int j = 0; j < 4; ++j) acc[i][j] = 0.f;

  const float* yb = y + (size_t)b * CIN * HH * WW;
  const float* nwb = nw + ((size_t)b * COUT + oc0) * WPS;

  for (int icb = 0; icb < CIN / 8; ++icb){
    const int ic0 = icb * 8;
    // stage y tile: 8 channels x 66 rows x 18 cols (halo, zero-padded)
    for (int li = tid; li < 8 * 66 * 18; li += 256){
      int c = li / (66 * 18); int r2 = li - c * 66 * 18;
      int row = r2 / 18; int col = r2 - row * 18;
      int gh = row - 1, gw = w0 + col - 1;
      float v = 0.f;
      if ((unsigned)gh < 64u && (unsigned)gw < 64u)
        v = yb[(ic0 + c) * HH * WW + gh * 64 + gw];
      yt[li] = v;
    }
    // stage weights: 8 oc x (8 ic x 9 taps)
    for (int li = tid; li < 8 * 8 * 9; li += 256){
      int oo = li / 72; int r = li - oo * 72;   // r = c*9 + t
      wt[li] = nwb[oo * WPS + ic0 * 9 + r];
    }
    __syncthreads();
    for (int c = 0; c < 8; ++c){
      float yv[4][9];
      #pragma unroll
      for (int j = 0; j < 4; ++j){
        const int hh = ty + 16 * j;   // tile row base (output h)
        #pragma unroll
        for (int dh = 0; dh < 3; ++dh)
          #pragma unroll
          for (int dw = 0; dw < 3; ++dw)
            yv[j][dh * 3 + dw] = yt[c * 1188 + (hh + dh) * 18 + tx + dw];
      }
      #pragma unroll
      for (int oo = 0; oo < 8; ++oo){
        #pragma unroll
        for (int t = 0; t < 9; ++t){
          const float wv = wt[(oo * 8 + c) * 9 + t];
          #pragma unroll
          for (int j = 0; j < 4; ++j) acc[oo][j] = fmaf(yv[j][t], wv, acc[oo][j]);
        }
      }
    }
    __syncthreads();
  }
  #pragma unroll
  for (int oo = 0; oo < 8; ++oo){
    const float bb = nbias[b * COUT + oc0 + oo];
    #pragma unroll
    for (int j = 0; j < 4; ++j){
      const int hh = ty + 16 * j;
      out[((size_t)(b * COUT + oc0 + oo)) * HH * WW + hh * 64 + w0 + tx] = acc[oo][j] + bb;
    }
  }
}

extern "C" void kernel_launch(void* const* d_in, const int* in_sizes, int n_in,
                              void* d_out, int out_size, void* d_ws, size_t ws_size,
                              hipStream_t stream){
  const float* y      = (const float*)d_in[0];
  const float* finger = (const float*)d_in[1];
  const float* ow     = (const float*)d_in[2];
  const float* wmask  = (const float*)d_in[3];
  const float* fwgt   = (const float*)d_in[4];
  const float* sw1    = (const float*)d_in[5];
  const float* sw2    = (const float*)d_in[6];
  const float* obias  = (const float*)d_in[7];
  const float* bmask  = (const float*)d_in[8];
  const float* fbias  = (const float*)d_in[9];
  const float* bw1    = (const float*)d_in[10];
  const float* bw2    = (const float*)d_in[11];
  float* out = (float*)d_out;
  float* ws  = (float*)d_ws;

  float* stat  = ws + OFF_STAT;
  float* bmean = ws + OFF_BMEAN;
  float* bstd  = ws + OFF_BSTD;
  float* ops   = ws + OFF_OPS;
  float* opq   = ws + OFF_OPQ;
  float* ps    = ws + OFF_PS;
  float* pq    = ws + OFF_PQ;
  float* h     = ws + OFF_H;
  float* style = ws + OFF_STYLE;
  float* nbias = ws + OFF_NBIAS;
  float* nw    = ws + OFF_NW;

  // global weight stats
  k_ori_part<<<NPART, 256, 0, stream>>>(ow, ops, opq);
  k_ori_final<<<1, 64, 0, stream>>>(ops, opq, stat);
  // style MLP
  k_style_h<<<(B * LAT + 255) / 256, 256, 0, stream>>>(finger, sw1, h);
  k_style<<<(B * 2 * WPS + 255) / 256, 256, 0, stream>>>(h, sw2, style);
  // bias path
  k_bias<<<B, COUT, 0, stream>>>(finger, bw1, bw2, fbias, bmask, obias, nbias);
  // per-sample stats
  k_w1_part<<<dim3(NPART, B), 256, 0, stream>>>(ow, fwgt, wmask, style, ps, pq);
  k_w1_final<<<B, 64, 0, stream>>>(ps, pq, bmean, bstd);
  // materialize new_weight
  k_new_weight<<<8192, 256, 0, stream>>>(ow, fwgt, wmask, style, stat, bmean, bstd, nw);
  // conv
  k_conv<<<dim3(4, 32, 16), 256, 0, stream>>>(y, nw, nbias, out);
}

// Round 2
// 316.181 us; speedup vs baseline: 5.6026x; 5.6026x over previous
//
#include <hip/hip_runtime.h>
#include <math.h>

#define LSLOPE 0.01f

__device__ __forceinline__ float lrelu(float x){ return x >= 0.f ? x : LSLOPE * x; }

typedef __attribute__((ext_vector_type(8))) short short8;
typedef __attribute__((ext_vector_type(4))) float f32x4;

__device__ __forceinline__ unsigned short f2bf(float f){
  union { float f; unsigned u; } v; v.f = f;
  unsigned r = v.u + 0x7FFFu + ((v.u >> 16) & 1u);
  return (unsigned short)(r >> 16);
}

constexpr int B    = 16;
constexpr int CIN  = 256;
constexpr int COUT = 256;
constexpr int HH   = 64;
constexpr int WW   = 64;
constexpr int KK   = 3;
constexpr int FD   = 128;
constexpr int LAT  = 128;
constexpr int WPS  = CIN * KK * KK;     // 2304 weights per (b, oc)
constexpr int WTOT = COUT * WPS;        // 589824 weights per sample
constexpr int NPART = 64;               // partial-reduction slots

// ---- workspace layout (in floats) ----
constexpr int OFF_STAT  = 0;            // [2]  mean_ori, std_ori
constexpr int OFF_BMEAN = 16;           // [16]
constexpr int OFF_BSTD  = 32;           // [16]
constexpr int OFF_OPS   = 64;           // [64]
constexpr int OFF_OPQ   = 128;          // [64]
constexpr int OFF_PS    = 192;          // [16*64]
constexpr int OFF_PQ    = 1216;         // [16*64]
constexpr int OFF_H     = 2240;         // [16*128]
constexpr int OFF_STYLE = 4288;         // [16*4608]
constexpr int OFF_NBIAS = 78016;        // [16*256]
constexpr int OFF_NW    = 82176;        // bf16 [16][9][256][256] = 9.44M ushort

// ---------- global weight stats (two-stage, deterministic) ----------
__global__ void k_ori_part(const float* __restrict__ ow, float* psum, float* psq){
  const int p = blockIdx.x;
  const int chunk = WTOT / NPART;
  const int base = p * chunk;
  float s = 0.f, q = 0.f;
  for (int i = threadIdx.x; i < chunk; i += 256){
    float v = ow[base + i];
    s += v; q += v * v;
  }
  __shared__ float ss[256], sq[256];
  ss[threadIdx.x] = s; sq[threadIdx.x] = q; __syncthreads();
  for (int st = 128; st > 0; st >>= 1){
    if (threadIdx.x < st){ ss[threadIdx.x] += ss[threadIdx.x + st]; sq[threadIdx.x] += sq[threadIdx.x + st]; }
    __syncthreads();
  }
  if (threadIdx.x == 0){ psum[p] = ss[0]; psq[p] = sq[0]; }
}

__global__ void k_ori_final(const float* __restrict__ psum, const float* __restrict__ psq, float* stat){
  int t = threadIdx.x;
  float s = psum[t], q = psq[t];
  for (int o = 32; o > 0; o >>= 1){ s += __shfl_down(s, o); q += __shfl_down(q, o); }
  if (t == 0){
    const float N = (float)WTOT;
    stat[0] = s / N;
    stat[1] = sqrtf((q - s * s / N) / (N - 1.f));
  }
}

// ---------- style MLP ----------
__global__ void k_style_h(const float* __restrict__ finger, const float* __restrict__ sw1, float* __restrict__ h){
  int idx = blockIdx.x * blockDim.x + threadIdx.x;
  if (idx >= B * LAT) return;
  int b = idx / LAT, l = idx - b * LAT;
  float acc = 0.f;
  for (int f = 0; f < FD; ++f) acc += finger[b * FD + f] * sw1[l * FD + f];
  h[idx] = lrelu(acc);
}

__global__ void k_style(const float* __restrict__ h, const float* __restrict__ sw2, float* __restrict__ style){
  int idx = blockIdx.x * blockDim.x + threadIdx.x;
  if (idx >= B * 2 * WPS) return;
  int b = idx / (2 * WPS), j = idx - b * 2 * WPS;
  float acc = 0.f;
  for (int l = 0; l < LAT; ++l) acc += h[b * LAT + l] * sw2[j * LAT + l];
  style[idx] = acc;
}

// ---------- per-sample bias ----------
__global__ void k_bias(const float* __restrict__ finger, const float* __restrict__ bw1,
                       const float* __restrict__ bw2, const float* __restrict__ fbias,
                       const float* __restrict__ bmask, const float* __restrict__ obias,
                       float* __restrict__ nbias){
  __shared__ float hb[COUT];
  const int b = blockIdx.x, o = threadIdx.x;
  float acc = 0.f;
  for (int f = 0; f < FD; ++f) acc += finger[b * FD + f] * bw1[o * FD + f];
  hb[o] = lrelu(acc);
  __syncthreads();
  float t = 0.f;
  for (int c = 0; c < COUT; ++c) t += hb[c] * bw2[o * COUT + c];
  t = lrelu(t);
  float sb = fbias[o] * t;
  float fwb = (6.f - fminf(fmaxf(bmask[o], 0.f), 6.f)) * (1.f / 6.f);
  nbias[b * COUT + o] = (1.f - fwb) * obias[o] + fwb * sb;
}

// ---------- per-sample w1 stats ----------
__global__ void k_w1_part(const float* __restrict__ ow, const float* __restrict__ fwgt,
                          const float* __restrict__ wmask, const float* __restrict__ style,
                          float* psum, float* psq){
  const int p = blockIdx.x, b = blockIdx.y;
  const float* st = style + b * 2 * WPS;
  const int chunk = WTOT / NPART;
  const int base = p * chunk;
  float s = 0.f, q = 0.f;
  for (int ii = threadIdx.x; ii < chunk; ii += 256){
    int idx = base + ii;
    int o = idx / WPS; int rem = idx - o * WPS; int ci = rem / 9;
    float fw = (6.f - fminf(fmaxf(wmask[o * CIN + ci], 0.f), 6.f)) * (1.f / 6.f);
    float owv = ow[idx];
    float sw = fwgt[idx] * (st[rem] + 1.f) + st[WPS + rem];
    float w1 = owv + fw * (sw - owv);
    s += w1; q += w1 * w1;
  }
  __shared__ float ss[256], sq[256];
  ss[threadIdx.x] = s; sq[threadIdx.x] = q; __syncthreads();
  for (int st2 = 128; st2 > 0; st2 >>= 1){
    if (threadIdx.x < st2){ ss[threadIdx.x] += ss[threadIdx.x + st2]; sq[threadIdx.x] += sq[threadIdx.x + st2]; }
    __syncthreads();
  }
  if (threadIdx.x == 0){ psum[b * NPART + p] = ss[0]; psq[b * NPART + p] = sq[0]; }
}

__global__ void k_w1_final(const float* __restrict__ psum, const float* __restrict__ psq,
                           float* bmean, float* bstd){
  const int b = blockIdx.x;
  int t = threadIdx.x;
  float s = psum[b * NPART + t], q = psq[b * NPART + t];
  for (int o = 32; o > 0; o >>= 1){ s += __shfl_down(s, o); q += __shfl_down(q, o); }
  if (t == 0){
    const float N = (float)WTOT;
    bmean[b] = s / N;
    bstd[b] = sqrtf((q - s * s / N) / (N - 1.f));
  }
}

// ---------- materialize new_weight in bf16, tap-major [b][t][oc][ic] ----------
__global__ void k_new_weight_bf16(const float* __restrict__ ow, const float* __restrict__ fwgt,
                                  const float* __restrict__ wmask, const float* __restrict__ style,
                                  const float* __restrict__ stat, const float* __restrict__ bmean,
                                  const float* __restrict__ bstd, unsigned short* __restrict__ nw){
  const int total = B * 9 * COUT * CIN;
  const float mean_ori = stat[0], std_ori = stat[1];
  for (int idx = blockIdx.x * blockDim.x + threadIdx.x; idx < total; idx += gridDim.x * blockDim.x){
    int ic = idx & 255; int tmp = idx >> 8;
    int oc = tmp & 255; tmp >>= 8;
    int t = tmp % 9; int b = tmp / 9;
    int rem = ic * 9 + t;            // index within [Cin,K,K] for this oc
    int r = oc * WPS + rem;          // index into ori_weight
    const float* st = style + b * 2 * WPS;
    float fw = (6.f - fminf(fmaxf(wmask[oc * CIN + ic], 0.f), 6.f)) * (1.f / 6.f);
    float owv = ow[r];
    float sw = fwgt[r] * (st[rem] + 1.f) + st[WPS + rem];
    float w1 = owv + fw * (sw - owv);
    float w2 = (w1 - bmean[b]) / bstd[b] * std_ori + mean_ori;
    nw[idx] = f2bf(owv + fw * (w2 - owv));
  }
}

// ---------- MFMA implicit-GEMM conv ----------
// grid (32 hw-tiles, 2 oc-tiles, 16 b); 256 threads = 4 waves (2x2).
// Tile: 128 oc x 128 hw (2 h-rows x 64 w). K loop: 9 taps x 8 ic-chunks of 32.
__global__ __launch_bounds__(256) void k_conv_mfma(const float* __restrict__ y,
                                                   const unsigned short* __restrict__ nw,
                                                   const float* __restrict__ nbias,
                                                   float* __restrict__ out){
  constexpr int PAD = 40;            // padded ic stride (bf16 elems)
  __shared__ unsigned short Wa[128 * PAD];
  __shared__ unsigned short Xb[128 * PAD];
  __shared__ float bsh[128];

  const int hwt = blockIdx.x;        // 0..31
  const int oc0 = blockIdx.y * 128;  // 0 / 128
  const int b   = blockIdx.z;
  const int tid = threadIdx.x;
  const int lane = tid & 63, wid = tid >> 6;
  const int wr = wid >> 1, wc = wid & 1;
  const int hw0 = hwt * 128;
  const int h0  = hwt * 2;

  if (tid < 128) bsh[tid] = nbias[b * COUT + oc0 + tid];

  f32x4 acc[4][4];
  #pragma unroll
  for (int i = 0; i < 4; ++i)
    #pragma unroll
    for (int j = 0; j < 4; ++j) acc[i][j] = (f32x4){0.f, 0.f, 0.f, 0.f};

  const float* yb = y + (size_t)b * CIN * HH * WW;

  // B-gather thread mapping
  const int hw_local = tid >> 1, icg = tid & 1;
  const int hrow = hw_local >> 6, wcol = hw_local & 63;

  for (int t = 0; t < 9; ++t){
    const int dh = t / 3 - 1, dw = t % 3 - 1;
    const int gh = h0 + hrow + dh;
    const int gw = wcol + dw;
    const bool ok = ((unsigned)gh < 64u) && ((unsigned)gw < 64u);
    const unsigned short* nwt = nw + ((size_t)(b * 9 + t) * COUT + oc0) * CIN;
    const float* ysrcb = yb + (size_t)icg * 16 * HH * WW + gh * 64 + gw;

    for (int icb = 0; icb < 8; ++icb){
      const int ic0 = icb * 32;
      __syncthreads();
      // stage A: 128 oc x 32 ic
      {
        int c = tid;
        #pragma unroll
        for (int rep = 0; rep < 2; ++rep, c += 256){
          int row = c >> 2, colb = (c & 3) * 8;
          const uint4 v = *(const uint4*)(nwt + (size_t)row * CIN + ic0 + colb);
          *(uint4*)(&Wa[row * PAD + colb]) = v;
        }
      }
      // stage B: X^T [128 hw][32 ic], gathered with tap shift, fp32->bf16
      {
        unsigned short us[16];
        const float* ysrc = ysrcb + (size_t)ic0 * HH * WW;
        if (ok){
          #pragma unroll
          for (int j = 0; j < 16; ++j) us[j] = f2bf(ysrc[(size_t)j * HH * WW]);
        } else {
          #pragma unroll
          for (int j = 0; j < 16; ++j) us[j] = 0;
        }
        *(uint4*)(&Xb[hw_local * PAD + icg * 16]) = *(uint4*)&us[0];
        *(uint4*)(&Xb[hw_local * PAD + icg * 16 + 8]) = *(uint4*)&us[8];
      }
      __syncthreads();
      // compute: 4x4 fragments of 16x16x32
      short8 af[4], bfr[4];
      #pragma unroll
      for (int mi = 0; mi < 4; ++mi)
        af[mi] = *(const short8*)&Wa[(wr * 64 + mi * 16 + (lane & 15)) * PAD + (lane >> 4) * 8];
      #pragma unroll
      for (int ni = 0; ni < 4; ++ni)
        bfr[ni] = *(const short8*)&Xb[(wc * 64 + ni * 16 + (lane & 15)) * PAD + (lane >> 4) * 8];
      #pragma unroll
      for (int mi = 0; mi < 4; ++mi)
        #pragma unroll
        for (int ni = 0; ni < 4; ++ni)
          acc[mi][ni] = __builtin_amdgcn_mfma_f32_16x16x32_bf16(af[mi], bfr[ni], acc[mi][ni], 0, 0, 0);
    }
  }

  // epilogue: D lane layout col=lane&15 (hw), row=(lane>>4)*4+reg (oc)
  const int col_l = lane & 15, row_l = (lane >> 4) * 4;
  #pragma unroll
  for (int mi = 0; mi < 4; ++mi){
    #pragma unroll
    for (int r = 0; r < 4; ++r){
      const int ocl = wr * 64 + mi * 16 + row_l + r;
      const float bb = bsh[ocl];
      float* op = out + ((size_t)(b * COUT + oc0 + ocl)) * (HH * WW) + hw0 + wc * 64;
      #pragma unroll
      for (int ni = 0; ni < 4; ++ni)
        op[ni * 16 + col_l] = acc[mi][ni][r] + bb;
    }
  }
}

extern "C" void kernel_launch(void* const* d_in, const int* in_sizes, int n_in,
                              void* d_out, int out_size, void* d_ws, size_t ws_size,
                              hipStream_t stream){
  const float* y      = (const float*)d_in[0];
  const float* finger = (const float*)d_in[1];
  const float* ow     = (const float*)d_in[2];
  const float* wmask  = (const float*)d_in[3];
  const float* fwgt   = (const float*)d_in[4];
  const float* sw1    = (const float*)d_in[5];
  const float* sw2    = (const float*)d_in[6];
  const float* obias  = (const float*)d_in[7];
  const float* bmask  = (const float*)d_in[8];
  const float* fbias  = (const float*)d_in[9];
  const float* bw1    = (const float*)d_in[10];
  const float* bw2    = (const float*)d_in[11];
  float* out = (float*)d_out;
  float* ws  = (float*)d_ws;

  float* stat  = ws + OFF_STAT;
  float* bmean = ws + OFF_BMEAN;
  float* bstd  = ws + OFF_BSTD;
  float* ops   = ws + OFF_OPS;
  float* opq   = ws + OFF_OPQ;
  float* ps    = ws + OFF_PS;
  float* pq    = ws + OFF_PQ;
  float* h     = ws + OFF_H;
  float* style = ws + OFF_STYLE;
  float* nbias = ws + OFF_NBIAS;
  unsigned short* nw = (unsigned short*)(ws + OFF_NW);

  k_ori_part<<<NPART, 256, 0, stream>>>(ow, ops, opq);
  k_ori_final<<<1, 64, 0, stream>>>(ops, opq, stat);
  k_style_h<<<(B * LAT + 255) / 256, 256, 0, stream>>>(finger, sw1, h);
  k_style<<<(B * 2 * WPS + 255) / 256, 256, 0, stream>>>(h, sw2, style);
  k_bias<<<B, COUT, 0, stream>>>(finger, bw1, bw2, fbias, bmask, obias, nbias);
  k_w1_part<<<dim3(NPART, B), 256, 0, stream>>>(ow, fwgt, wmask, style, ps, pq);
  k_w1_final<<<B, 64, 0, stream>>>(ps, pq, bmean, bstd);
  k_new_weight_bf16<<<4608, 256, 0, stream>>>(ow, fwgt, wmask, style, stat, bmean, bstd, nw);
  k_conv_mfma<<<dim3(32, 2, 16), 256, 0, stream>>>(y, nw, nbias, out);
}

// Round 3
// 263.905 us; speedup vs baseline: 6.7124x; 1.1981x over previous
//
#include <hip/hip_runtime.h>
#include <math.h>

#define LSLOPE 0.01f

__device__ __forceinline__ float lrelu(float x){ return x >= 0.f ? x : LSLOPE * x; }

typedef __attribute__((ext_vector_type(8))) short short8;
typedef __attribute__((ext_vector_type(4))) float f32x4;

__device__ __forceinline__ unsigned short f2bf(float f){
  union { float f; unsigned u; } v; v.f = f;
  unsigned r = v.u + 0x7FFFu + ((v.u >> 16) & 1u);
  return (unsigned short)(r >> 16);
}

constexpr int B    = 16;
constexpr int CIN  = 256;
constexpr int COUT = 256;
constexpr int HH   = 64;
constexpr int WW   = 64;
constexpr int KK   = 3;
constexpr int FD   = 128;
constexpr int LAT  = 128;
constexpr int WPS  = CIN * KK * KK;     // 2304
constexpr int WTOT = COUT * WPS;        // 589824
constexpr int NPART = 64;

// ---- workspace layout (in floats) ----
constexpr int OFF_STAT  = 0;
constexpr int OFF_BMEAN = 16;
constexpr int OFF_BSTD  = 32;
constexpr int OFF_OPS   = 64;
constexpr int OFF_OPQ   = 128;
constexpr int OFF_PS    = 192;
constexpr int OFF_PQ    = 1216;
constexpr int OFF_H     = 2240;
constexpr int OFF_STYLE = 4288;
constexpr int OFF_NBIAS = 78016;
constexpr int OFF_NW    = 82176;                       // bf16 [16][9][256][256] = 9.44M ushort
constexpr int OFF_YTR   = OFF_NW + (B * 9 * COUT * CIN) / 2;   // bf16 [16][64][64][256] = 16.78M ushort

// ---------- global weight stats ----------
__global__ void k_ori_part(const float* __restrict__ ow, float* psum, float* psq){
  const int p = blockIdx.x;
  const int chunk = WTOT / NPART;
  const int base = p * chunk;
  float s = 0.f, q = 0.f;
  for (int i = threadIdx.x; i < chunk; i += 256){
    float v = ow[base + i];
    s += v; q += v * v;
  }
  __shared__ float ss[256], sq[256];
  ss[threadIdx.x] = s; sq[threadIdx.x] = q; __syncthreads();
  for (int st = 128; st > 0; st >>= 1){
    if (threadIdx.x < st){ ss[threadIdx.x] += ss[threadIdx.x + st]; sq[threadIdx.x] += sq[threadIdx.x + st]; }
    __syncthreads();
  }
  if (threadIdx.x == 0){ psum[p] = ss[0]; psq[p] = sq[0]; }
}

__global__ void k_ori_final(const float* __restrict__ psum, const float* __restrict__ psq, float* stat){
  int t = threadIdx.x;
  float s = psum[t], q = psq[t];
  for (int o = 32; o > 0; o >>= 1){ s += __shfl_down(s, o); q += __shfl_down(q, o); }
  if (t == 0){
    const float N = (float)WTOT;
    stat[0] = s / N;
    stat[1] = sqrtf((q - s * s / N) / (N - 1.f));
  }
}

// ---------- style MLP ----------
__global__ void k_style_h(const float* __restrict__ finger, const float* __restrict__ sw1, float* __restrict__ h){
  int idx = blockIdx.x * blockDim.x + threadIdx.x;
  if (idx >= B * LAT) return;
  int b = idx / LAT, l = idx - b * LAT;
  float acc = 0.f;
  for (int f = 0; f < FD; ++f) acc += finger[b * FD + f] * sw1[l * FD + f];
  h[idx] = lrelu(acc);
}

__global__ void k_style(const float* __restrict__ h, const float* __restrict__ sw2, float* __restrict__ style){
  int idx = blockIdx.x * blockDim.x + threadIdx.x;
  if (idx >= B * 2 * WPS) return;
  int b = idx / (2 * WPS), j = idx - b * 2 * WPS;
  float acc = 0.f;
  for (int l = 0; l < LAT; ++l) acc += h[b * LAT + l] * sw2[j * LAT + l];
  style[idx] = acc;
}

// ---------- per-sample bias ----------
__global__ void k_bias(const float* __restrict__ finger, const float* __restrict__ bw1,
                       const float* __restrict__ bw2, const float* __restrict__ fbias,
                       const float* __restrict__ bmask, const float* __restrict__ obias,
                       float* __restrict__ nbias){
  __shared__ float hb[COUT];
  const int b = blockIdx.x, o = threadIdx.x;
  float acc = 0.f;
  for (int f = 0; f < FD; ++f) acc += finger[b * FD + f] * bw1[o * FD + f];
  hb[o] = lrelu(acc);
  __syncthreads();
  float t = 0.f;
  for (int c = 0; c < COUT; ++c) t += hb[c] * bw2[o * COUT + c];
  t = lrelu(t);
  float sb = fbias[o] * t;
  float fwb = (6.f - fminf(fmaxf(bmask[o], 0.f), 6.f)) * (1.f / 6.f);
  nbias[b * COUT + o] = (1.f - fwb) * obias[o] + fwb * sb;
}

// ---------- per-sample w1 stats ----------
__global__ void k_w1_part(const float* __restrict__ ow, const float* __restrict__ fwgt,
                          const float* __restrict__ wmask, const float* __restrict__ style,
                          float* psum, float* psq){
  const int p = blockIdx.x, b = blockIdx.y;
  const float* st = style + b * 2 * WPS;
  const int chunk = WTOT / NPART;
  const int base = p * chunk;
  float s = 0.f, q = 0.f;
  for (int ii = threadIdx.x; ii < chunk; ii += 256){
    int idx = base + ii;
    int o = idx / WPS; int rem = idx - o * WPS; int ci = rem / 9;
    float fw = (6.f - fminf(fmaxf(wmask[o * CIN + ci], 0.f), 6.f)) * (1.f / 6.f);
    float owv = ow[idx];
    float sw = fwgt[idx] * (st[rem] + 1.f) + st[WPS + rem];
    float w1 = owv + fw * (sw - owv);
    s += w1; q += w1 * w1;
  }
  __shared__ float ss[256], sq[256];
  ss[threadIdx.x] = s; sq[threadIdx.x] = q; __syncthreads();
  for (int st2 = 128; st2 > 0; st2 >>= 1){
    if (threadIdx.x < st2){ ss[threadIdx.x] += ss[threadIdx.x + st2]; sq[threadIdx.x] += sq[threadIdx.x + st2]; }
    __syncthreads();
  }
  if (threadIdx.x == 0){ psum[b * NPART + p] = ss[0]; psq[b * NPART + p] = sq[0]; }
}

__global__ void k_w1_final(const float* __restrict__ psum, const float* __restrict__ psq,
                           float* bmean, float* bstd){
  const int b = blockIdx.x;
  int t = threadIdx.x;
  float s = psum[b * NPART + t], q = psq[b * NPART + t];
  for (int o = 32; o > 0; o >>= 1){ s += __shfl_down(s, o); q += __shfl_down(q, o); }
  if (t == 0){
    const float N = (float)WTOT;
    bmean[b] = s / N;
    bstd[b] = sqrtf((q - s * s / N) / (N - 1.f));
  }
}

// ---------- materialize new_weight bf16, tap-major [b][t][oc][ic] ----------
__global__ void k_new_weight_bf16(const float* __restrict__ ow, const float* __restrict__ fwgt,
                                  const float* __restrict__ wmask, const float* __restrict__ style,
                                  const float* __restrict__ stat, const float* __restrict__ bmean,
                                  const float* __restrict__ bstd, unsigned short* __restrict__ nw){
  const int total = B * 9 * COUT * CIN;
  const float mean_ori = stat[0], std_ori = stat[1];
  for (int idx = blockIdx.x * blockDim.x + threadIdx.x; idx < total; idx += gridDim.x * blockDim.x){
    int ic = idx & 255; int tmp = idx >> 8;
    int oc = tmp & 255; tmp >>= 8;
    int t = tmp % 9; int b = tmp / 9;
    int rem = ic * 9 + t;
    int r = oc * WPS + rem;
    const float* st = style + b * 2 * WPS;
    float fw = (6.f - fminf(fmaxf(wmask[oc * CIN + ic], 0.f), 6.f)) * (1.f / 6.f);
    float owv = ow[r];
    float sw = fwgt[r] * (st[rem] + 1.f) + st[WPS + rem];
    float w1 = owv + fw * (sw - owv);
    float w2 = (w1 - bmean[b]) / bstd[b] * std_ori + mean_ori;
    nw[idx] = f2bf(owv + fw * (w2 - owv));
  }
}

// ---------- y -> channel-last bf16 transpose: ytr[b][h][w][ic] ----------
constexpr int PADT = 264;   // padded ic stride in LDS
__global__ __launch_bounds__(256) void k_ytr(const float* __restrict__ y, unsigned short* __restrict__ ytr){
  __shared__ unsigned short t[64 * PADT];
  const int h = blockIdx.x, b = blockIdx.y;
  const int tid = threadIdx.x;
  const float* src = y + (size_t)b * CIN * HH * WW + h * WW;
  #pragma unroll
  for (int k = 0; k < 16; ++k){
    int idx = tid + k * 256;
    int ic = idx >> 4, w4 = (idx & 15) * 4;
    float4 v = *(const float4*)(src + (size_t)ic * HH * WW + w4);
    t[(w4 + 0) * PADT + ic] = f2bf(v.x);
    t[(w4 + 1) * PADT + ic] = f2bf(v.y);
    t[(w4 + 2) * PADT + ic] = f2bf(v.z);
    t[(w4 + 3) * PADT + ic] = f2bf(v.w);
  }
  __syncthreads();
  unsigned short* dst = ytr + (((size_t)b * HH + h) * WW) * CIN;
  #pragma unroll
  for (int k = 0; k < 8; ++k){
    int idx = tid + k * 256;
    int w = idx >> 5, icg = (idx & 31) * 8;
    uint4 v = *(const uint4*)(&t[w * PADT + icg]);
    *(uint4*)(dst + (size_t)w * CIN + icg) = v;
  }
}

// ---------- MFMA implicit-GEMM conv, B staged from channel-last bf16 ----------
__global__ __launch_bounds__(256) void k_conv_mfma2(const unsigned short* __restrict__ ytr,
                                                    const unsigned short* __restrict__ nw,
                                                    const float* __restrict__ nbias,
                                                    float* __restrict__ out){
  constexpr int PAD = 40;
  __shared__ unsigned short Wa[128 * PAD];
  __shared__ unsigned short Xb[128 * PAD];
  __shared__ float bsh[128];

  const int hwt = blockIdx.x;
  const int oc0 = blockIdx.y * 128;
  const int b   = blockIdx.z;
  const int tid = threadIdx.x;
  const int lane = tid & 63, wid = tid >> 6;
  const int wr = wid >> 1, wc = wid & 1;
  const int hw0 = hwt * 128;
  const int h0  = hwt * 2;

  if (tid < 128) bsh[tid] = nbias[b * COUT + oc0 + tid];

  f32x4 acc[4][4];
  #pragma unroll
  for (int i = 0; i < 4; ++i)
    #pragma unroll
    for (int j = 0; j < 4; ++j) acc[i][j] = (f32x4){0.f, 0.f, 0.f, 0.f};

  const unsigned short* ytb = ytr + (size_t)b * HH * WW * CIN;
  const int hw_local = tid >> 1, half = tid & 1;
  const int hrow = hw_local >> 6, wcol = hw_local & 63;

  for (int t = 0; t < 9; ++t){
    const int dh = t / 3 - 1, dw = t % 3 - 1;
    const int gh = h0 + hrow + dh;
    const int gw = wcol + dw;
    const bool ok = ((unsigned)gh < 64u) && ((unsigned)gw < 64u);
    const unsigned short* nwt = nw + ((size_t)(b * 9 + t) * COUT + oc0) * CIN;
    const unsigned short* ysrc = ytb + ((size_t)(gh * 64 + gw)) * CIN + half * 16;

    for (int icb = 0; icb < 8; ++icb){
      const int ic0 = icb * 32;
      __syncthreads();
      // stage A: 128 oc x 32 ic
      {
        int c = tid;
        #pragma unroll
        for (int rep = 0; rep < 2; ++rep, c += 256){
          int row = c >> 2, colb = (c & 3) * 8;
          const uint4 v = *(const uint4*)(nwt + (size_t)row * CIN + ic0 + colb);
          *(uint4*)(&Wa[row * PAD + colb]) = v;
        }
      }
      // stage B: X^T [128 hw][32 ic] from channel-last ytr (coalesced)
      if (ok){
        *(uint4*)(&Xb[hw_local * PAD + half * 16])     = *(const uint4*)(ysrc + ic0);
        *(uint4*)(&Xb[hw_local * PAD + half * 16 + 8]) = *(const uint4*)(ysrc + ic0 + 8);
      } else {
        *(uint4*)(&Xb[hw_local * PAD + half * 16])     = (uint4){0,0,0,0};
        *(uint4*)(&Xb[hw_local * PAD + half * 16 + 8]) = (uint4){0,0,0,0};
      }
      __syncthreads();
      short8 af[4], bfr[4];
      #pragma unroll
      for (int mi = 0; mi < 4; ++mi)
        af[mi] = *(const short8*)&Wa[(wr * 64 + mi * 16 + (lane & 15)) * PAD + (lane >> 4) * 8];
      #pragma unroll
      for (int ni = 0; ni < 4; ++ni)
        bfr[ni] = *(const short8*)&Xb[(wc * 64 + ni * 16 + (lane & 15)) * PAD + (lane >> 4) * 8];
      #pragma unroll
      for (int mi = 0; mi < 4; ++mi)
        #pragma unroll
        for (int ni = 0; ni < 4; ++ni)
          acc[mi][ni] = __builtin_amdgcn_mfma_f32_16x16x32_bf16(af[mi], bfr[ni], acc[mi][ni], 0, 0, 0);
    }
  }

  const int col_l = lane & 15, row_l = (lane >> 4) * 4;
  #pragma unroll
  for (int mi = 0; mi < 4; ++mi){
    #pragma unroll
    for (int r = 0; r < 4; ++r){
      const int ocl = wr * 64 + mi * 16 + row_l + r;
      const float bb = bsh[ocl];
      float* op = out + ((size_t)(b * COUT + oc0 + ocl)) * (HH * WW) + hw0 + wc * 64;
      #pragma unroll
      for (int ni = 0; ni < 4; ++ni)
        op[ni * 16 + col_l] = acc[mi][ni][r] + bb;
    }
  }
}

// ---------- fallback conv (round-2 path, gathers fp32 y directly) ----------
__global__ __launch_bounds__(256) void k_conv_mfma(const float* __restrict__ y,
                                                   const unsigned short* __restrict__ nw,
                                                   const float* __restrict__ nbias,
                                                   float* __restrict__ out){
  constexpr int PAD = 40;
  __shared__ unsigned short Wa[128 * PAD];
  __shared__ unsigned short Xb[128 * PAD];
  __shared__ float bsh[128];
  const int hwt = blockIdx.x;
  const int oc0 = blockIdx.y * 128;
  const int b   = blockIdx.z;
  const int tid = threadIdx.x;
  const int lane = tid & 63, wid = tid >> 6;
  const int wr = wid >> 1, wc = wid & 1;
  const int hw0 = hwt * 128;
  const int h0  = hwt * 2;
  if (tid < 128) bsh[tid] = nbias[b * COUT + oc0 + tid];
  f32x4 acc[4][4];
  #pragma unroll
  for (int i = 0; i < 4; ++i)
    #pragma unroll
    for (int j = 0; j < 4; ++j) acc[i][j] = (f32x4){0.f, 0.f, 0.f, 0.f};
  const float* yb = y + (size_t)b * CIN * HH * WW;
  const int hw_local = tid >> 1, icg = tid & 1;
  const int hrow = hw_local >> 6, wcol = hw_local & 63;
  for (int t = 0; t < 9; ++t){
    const int dh = t / 3 - 1, dw = t % 3 - 1;
    const int gh = h0 + hrow + dh;
    const int gw = wcol + dw;
    const bool ok = ((unsigned)gh < 64u) && ((unsigned)gw < 64u);
    const unsigned short* nwt = nw + ((size_t)(b * 9 + t) * COUT + oc0) * CIN;
    const float* ysrcb = yb + (size_t)icg * 16 * HH * WW + gh * 64 + gw;
    for (int icb = 0; icb < 8; ++icb){
      const int ic0 = icb * 32;
      __syncthreads();
      {
        int c = tid;
        #pragma unroll
        for (int rep = 0; rep < 2; ++rep, c += 256){
          int row = c >> 2, colb = (c & 3) * 8;
          const uint4 v = *(const uint4*)(nwt + (size_t)row * CIN + ic0 + colb);
          *(uint4*)(&Wa[row * PAD + colb]) = v;
        }
      }
      {
        unsigned short us[16];
        const float* ysrc = ysrcb + (size_t)ic0 * HH * WW;
        if (ok){
          #pragma unroll
          for (int j = 0; j < 16; ++j) us[j] = f2bf(ysrc[(size_t)j * HH * WW]);
        } else {
          #pragma unroll
          for (int j = 0; j < 16; ++j) us[j] = 0;
        }
        *(uint4*)(&Xb[hw_local * PAD + icg * 16]) = *(uint4*)&us[0];
        *(uint4*)(&Xb[hw_local * PAD + icg * 16 + 8]) = *(uint4*)&us[8];
      }
      __syncthreads();
      short8 af[4], bfr[4];
      #pragma unroll
      for (int mi = 0; mi < 4; ++mi)
        af[mi] = *(const short8*)&Wa[(wr * 64 + mi * 16 + (lane & 15)) * PAD + (lane >> 4) * 8];
      #pragma unroll
      for (int ni = 0; ni < 4; ++ni)
        bfr[ni] = *(const short8*)&Xb[(wc * 64 + ni * 16 + (lane & 15)) * PAD + (lane >> 4) * 8];
      #pragma unroll
      for (int mi = 0; mi < 4; ++mi)
        #pragma unroll
        for (int ni = 0; ni < 4; ++ni)
          acc[mi][ni] = __builtin_amdgcn_mfma_f32_16x16x32_bf16(af[mi], bfr[ni], acc[mi][ni], 0, 0, 0);
    }
  }
  const int col_l = lane & 15, row_l = (lane >> 4) * 4;
  #pragma unroll
  for (int mi = 0; mi < 4; ++mi){
    #pragma unroll
    for (int r = 0; r < 4; ++r){
      const int ocl = wr * 64 + mi * 16 + row_l + r;
      const float bb = bsh[ocl];
      float* op = out + ((size_t)(b * COUT + oc0 + ocl)) * (HH * WW) + hw0 + wc * 64;
      #pragma unroll
      for (int ni = 0; ni < 4; ++ni)
        op[ni * 16 + col_l] = acc[mi][ni][r] + bb;
    }
  }
}

extern "C" void kernel_launch(void* const* d_in, const int* in_sizes, int n_in,
                              void* d_out, int out_size, void* d_ws, size_t ws_size,
                              hipStream_t stream){
  const float* y      = (const float*)d_in[0];
  const float* finger = (const float*)d_in[1];
  const float* ow     = (const float*)d_in[2];
  const float* wmask  = (const float*)d_in[3];
  const float* fwgt   = (const float*)d_in[4];
  const float* sw1    = (const float*)d_in[5];
  const float* sw2    = (const float*)d_in[6];
  const float* obias  = (const float*)d_in[7];
  const float* bmask  = (const float*)d_in[8];
  const float* fbias  = (const float*)d_in[9];
  const float* bw1    = (const float*)d_in[10];
  const float* bw2    = (const float*)d_in[11];
  float* out = (float*)d_out;
  float* ws  = (float*)d_ws;

  float* stat  = ws + OFF_STAT;
  float* bmean = ws + OFF_BMEAN;
  float* bstd  = ws + OFF_BSTD;
  float* ops   = ws + OFF_OPS;
  float* opq   = ws + OFF_OPQ;
  float* ps    = ws + OFF_PS;
  float* pq    = ws + OFF_PQ;
  float* h     = ws + OFF_H;
  float* style = ws + OFF_STYLE;
  float* nbias = ws + OFF_NBIAS;
  unsigned short* nw  = (unsigned short*)(ws + OFF_NW);
  unsigned short* ytr = (unsigned short*)(ws + OFF_YTR);

  const size_t need_bytes = ((size_t)OFF_YTR + (size_t)B * HH * WW * CIN / 2) * 4;
  const bool use_ytr = ws_size >= need_bytes;

  k_ori_part<<<NPART, 256, 0, stream>>>(ow, ops, opq);
  k_ori_final<<<1, 64, 0, stream>>>(ops, opq, stat);
  k_style_h<<<(B * LAT + 255) / 256, 256, 0, stream>>>(finger, sw1, h);
  k_style<<<(B * 2 * WPS + 255) / 256, 256, 0, stream>>>(h, sw2, style);
  k_bias<<<B, COUT, 0, stream>>>(finger, bw1, bw2, fbias, bmask, obias, nbias);
  k_w1_part<<<dim3(NPART, B), 256, 0, stream>>>(ow, fwgt, wmask, style, ps, pq);
  k_w1_final<<<B, 64, 0, stream>>>(ps, pq, bmean, bstd);
  k_new_weight_bf16<<<4608, 256, 0, stream>>>(ow, fwgt, wmask, style, stat, bmean, bstd, nw);
  if (use_ytr){
    k_ytr<<<dim3(HH, B), 256, 0, stream>>>(y, ytr);
    k_conv_mfma2<<<dim3(32, 2, 16), 256, 0, stream>>>(ytr, nw, nbias, out);
  } else {
    k_conv_mfma<<<dim3(32, 2, 16), 256, 0, stream>>>(y, nw, nbias, out);
  }
}

// Round 4
// 199.170 us; speedup vs baseline: 8.8941x; 1.3250x over previous
//
#include <hip/hip_runtime.h>
#include <math.h>

#define LSLOPE 0.01f

__device__ __forceinline__ float lrelu(float x){ return x >= 0.f ? x : LSLOPE * x; }

typedef __attribute__((ext_vector_type(8))) short short8;
typedef __attribute__((ext_vector_type(4))) float f32x4;

__device__ __forceinline__ unsigned short f2bf(float f){
  union { float f; unsigned u; } v; v.f = f;
  unsigned r = v.u + 0x7FFFu + ((v.u >> 16) & 1u);
  return (unsigned short)(r >> 16);
}

constexpr int B    = 16;
constexpr int CIN  = 256;
constexpr int COUT = 256;
constexpr int HH   = 64;
constexpr int WW   = 64;
constexpr int FD   = 128;
constexpr int LAT  = 128;
constexpr int WPS  = CIN * 9;           // 2304
constexpr int WTOT = COUT * WPS;        // 589824
constexpr int NPART = 64;

// ---- workspace layout (in floats) ----
constexpr int OFF_STAT  = 0;
constexpr int OFF_BMEAN = 16;
constexpr int OFF_BSTD  = 32;
constexpr int OFF_OPS   = 64;
constexpr int OFF_OPQ   = 128;
constexpr int OFF_PS    = 192;
constexpr int OFF_PQ    = 1216;
constexpr int OFF_H     = 2240;
constexpr int OFF_STYLE = 4288;
constexpr int OFF_NBIAS = 78016;
constexpr int OFF_NW    = 82176;                               // bf16 [16][9][256][256]
constexpr int OFF_YTR   = OFF_NW + (B * 9 * COUT * CIN) / 2;   // bf16 [16][64][64][256]

// ---------- global weight stats ----------
__global__ void k_ori_part(const float* __restrict__ ow, float* psum, float* psq){
  const int p = blockIdx.x;
  const int chunk = WTOT / NPART;
  const int base = p * chunk;
  float s = 0.f, q = 0.f;
  for (int i = threadIdx.x; i < chunk; i += 256){
    float v = ow[base + i];
    s += v; q += v * v;
  }
  __shared__ float ss[256], sq[256];
  ss[threadIdx.x] = s; sq[threadIdx.x] = q; __syncthreads();
  for (int st = 128; st > 0; st >>= 1){
    if (threadIdx.x < st){ ss[threadIdx.x] += ss[threadIdx.x + st]; sq[threadIdx.x] += sq[threadIdx.x + st]; }
    __syncthreads();
  }
  if (threadIdx.x == 0){ psum[p] = ss[0]; psq[p] = sq[0]; }
}

__global__ void k_ori_final(const float* __restrict__ psum, const float* __restrict__ psq, float* stat){
  int t = threadIdx.x;
  float s = psum[t], q = psq[t];
  for (int o = 32; o > 0; o >>= 1){ s += __shfl_down(s, o); q += __shfl_down(q, o); }
  if (t == 0){
    const float N = (float)WTOT;
    stat[0] = s / N;
    stat[1] = sqrtf((q - s * s / N) / (N - 1.f));
  }
}

// ---------- style MLP ----------
__global__ void k_style_h(const float* __restrict__ finger, const float* __restrict__ sw1, float* __restrict__ h){
  int idx = blockIdx.x * blockDim.x + threadIdx.x;
  if (idx >= B * LAT) return;
  int b = idx / LAT, l = idx - b * LAT;
  float acc = 0.f;
  for (int f = 0; f < FD; ++f) acc += finger[b * FD + f] * sw1[l * FD + f];
  h[idx] = lrelu(acc);
}

__global__ void k_style(const float* __restrict__ h, const float* __restrict__ sw2, float* __restrict__ style){
  int idx = blockIdx.x * blockDim.x + threadIdx.x;
  if (idx >= B * 2 * WPS) return;
  int b = idx / (2 * WPS), j = idx - b * 2 * WPS;
  float acc = 0.f;
  for (int l = 0; l < LAT; ++l) acc += h[b * LAT + l] * sw2[j * LAT + l];
  style[idx] = acc;
}

// ---------- per-sample bias ----------
__global__ void k_bias(const float* __restrict__ finger, const float* __restrict__ bw1,
                       const float* __restrict__ bw2, const float* __restrict__ fbias,
                       const float* __restrict__ bmask, const float* __restrict__ obias,
                       float* __restrict__ nbias){
  __shared__ float hb[COUT];
  const int b = blockIdx.x, o = threadIdx.x;
  float acc = 0.f;
  for (int f = 0; f < FD; ++f) acc += finger[b * FD + f] * bw1[o * FD + f];
  hb[o] = lrelu(acc);
  __syncthreads();
  float t = 0.f;
  for (int c = 0; c < COUT; ++c) t += hb[c] * bw2[o * COUT + c];
  t = lrelu(t);
  float sb = fbias[o] * t;
  float fwb = (6.f - fminf(fmaxf(bmask[o], 0.f), 6.f)) * (1.f / 6.f);
  nbias[b * COUT + o] = (1.f - fwb) * obias[o] + fwb * sb;
}

// ---------- per-sample w1 stats ----------
__global__ void k_w1_part(const float* __restrict__ ow, const float* __restrict__ fwgt,
                          const float* __restrict__ wmask, const float* __restrict__ style,
                          float* psum, float* psq){
  const int p = blockIdx.x, b = blockIdx.y;
  const float* st = style + b * 2 * WPS;
  const int chunk = WTOT / NPART;
  const int base = p * chunk;
  float s = 0.f, q = 0.f;
  for (int ii = threadIdx.x; ii < chunk; ii += 256){
    int idx = base + ii;
    int o = idx / WPS; int rem = idx - o * WPS; int ci = rem / 9;
    float fw = (6.f - fminf(fmaxf(wmask[o * CIN + ci], 0.f), 6.f)) * (1.f / 6.f);
    float owv = ow[idx];
    float sw = fwgt[idx] * (st[rem] + 1.f) + st[WPS + rem];
    float w1 = owv + fw * (sw - owv);
    s += w1; q += w1 * w1;
  }
  __shared__ float ss[256], sq[256];
  ss[threadIdx.x] = s; sq[threadIdx.x] = q; __syncthreads();
  for (int st2 = 128; st2 > 0; st2 >>= 1){
    if (threadIdx.x < st2){ ss[threadIdx.x] += ss[threadIdx.x + st2]; sq[threadIdx.x] += sq[threadIdx.x + st2]; }
    __syncthreads();
  }
  if (threadIdx.x == 0){ psum[b * NPART + p] = ss[0]; psq[b * NPART + p] = sq[0]; }
}

__global__ void k_w1_final(const float* __restrict__ psum, const float* __restrict__ psq,
                           float* bmean, float* bstd){
  const int b = blockIdx.x;
  int t = threadIdx.x;
  float s = psum[b * NPART + t], q = psq[b * NPART + t];
  for (int o = 32; o > 0; o >>= 1){ s += __shfl_down(s, o); q += __shfl_down(q, o); }
  if (t == 0){
    const float N = (float)WTOT;
    bmean[b] = s / N;
    bstd[b] = sqrtf((q - s * s / N) / (N - 1.f));
  }
}

// ---------- materialize new_weight bf16, tap-major [b][t][oc][ic], coalesced ----------
// One block per (oc, b). Stage ow/fwgt rows coalesced into LDS; thread = ic.
__global__ __launch_bounds__(256) void k_new_weight2(const float* __restrict__ ow, const float* __restrict__ fwgt,
                                                     const float* __restrict__ wmask, const float* __restrict__ style,
                                                     const float* __restrict__ stat, const float* __restrict__ bmean,
                                                     const float* __restrict__ bstd, unsigned short* __restrict__ nw){
  __shared__ float ows[WPS];
  __shared__ float fws[WPS];
  const int oc = blockIdx.x, b = blockIdx.y;
  const int tid = threadIdx.x;               // = ic
  const float mean_ori = stat[0], std_ori = stat[1];
  const float bm = bmean[b], bs = bstd[b];
  const float* owr = ow + (size_t)oc * WPS;
  const float* fwr = fwgt + (size_t)oc * WPS;
  for (int i = tid; i < WPS; i += 256){ ows[i] = owr[i]; fws[i] = fwr[i]; }
  const float fw = (6.f - fminf(fmaxf(wmask[oc * CIN + tid], 0.f), 6.f)) * (1.f / 6.f);
  const float* st = style + b * 2 * WPS;
  __syncthreads();
  #pragma unroll
  for (int t = 0; t < 9; ++t){
    int rem = tid * 9 + t;
    float owv = ows[rem];
    float sw = fws[rem] * (st[rem] + 1.f) + st[WPS + rem];
    float w1 = owv + fw * (sw - owv);
    float w2 = (w1 - bm) / bs * std_ori + mean_ori;
    nw[((size_t)(b * 9 + t) * COUT + oc) * CIN + tid] = f2bf(owv + fw * (w2 - owv));
  }
}

// ---------- y -> channel-last bf16: ytr[b][h][w][ic] ----------
constexpr int PADT = 264;
__global__ __launch_bounds__(256) void k_ytr(const float* __restrict__ y, unsigned short* __restrict__ ytr){
  __shared__ unsigned short t[64 * PADT];
  const int h = blockIdx.x, b = blockIdx.y;
  const int tid = threadIdx.x;
  const float* src = y + (size_t)b * CIN * HH * WW + h * WW;
  #pragma unroll
  for (int k = 0; k < 16; ++k){
    int idx = tid + k * 256;
    int ic = idx >> 4, w4 = (idx & 15) * 4;
    float4 v = *(const float4*)(src + (size_t)ic * HH * WW + w4);
    t[(w4 + 0) * PADT + ic] = f2bf(v.x);
    t[(w4 + 1) * PADT + ic] = f2bf(v.y);
    t[(w4 + 2) * PADT + ic] = f2bf(v.z);
    t[(w4 + 3) * PADT + ic] = f2bf(v.w);
  }
  __syncthreads();
  unsigned short* dst = ytr + (((size_t)b * HH + h) * WW) * CIN;
  #pragma unroll
  for (int k = 0; k < 8; ++k){
    int idx = tid + k * 256;
    int w = idx >> 5, icg = (idx & 31) * 8;
    uint4 v = *(const uint4*)(&t[w * PADT + icg]);
    *(uint4*)(dst + (size_t)w * CIN + icg) = v;
  }
}

// ---------- MFMA implicit-GEMM conv with y-tile reuse across dw taps ----------
// grid (32 hw-tiles, 2 oc-tiles, 16 b); 256 thr = 4 waves (2x2).
// Loop: dh(3) x icb(8): stage y-halo [2 rows][66 cols][32 ic] + A3 [3 taps][128 oc][32 ic];
// compute 3 dw-taps x 16 MFMA from LDS. 48 MFMA per barrier pair.
__global__ __launch_bounds__(256) void k_conv_mfma3(const unsigned short* __restrict__ ytr,
                                                    const unsigned short* __restrict__ nw,
                                                    const float* __restrict__ nbias,
                                                    float* __restrict__ out){
  constexpr int APAD = 44;   // A ic-stride (ushorts): 88B = 22-bank starts, distinct
  constexpr int BPAD = 36;   // B ic-stride (ushorts): 72B = 18-bank starts, distinct
  __shared__ unsigned short Wa[3 * 128 * APAD];   // 33792 B
  __shared__ unsigned short Yt[2 * 68 * BPAD];    //  9792 B
  __shared__ float bsh[128];

  const int hwt = blockIdx.x;
  const int oc0 = blockIdx.y * 128;
  const int b   = blockIdx.z;
  const int tid = threadIdx.x;
  const int lane = tid & 63, wid = tid >> 6;
  const int wr = wid >> 1, wc = wid & 1;
  const int hw0 = hwt * 128;
  const int h0  = hwt * 2;

  if (tid < 128) bsh[tid] = nbias[b * COUT + oc0 + tid];

  f32x4 acc[4][4];
  #pragma unroll
  for (int i = 0; i < 4; ++i)
    #pragma unroll
    for (int j = 0; j < 4; ++j) acc[i][j] = (f32x4){0.f, 0.f, 0.f, 0.f};

  // precomputed fragment LDS addresses (ushort indices)
  int aaddr[3][4], baddr[3][4];
  #pragma unroll
  for (int tap = 0; tap < 3; ++tap){
    #pragma unroll
    for (int mi = 0; mi < 4; ++mi)
      aaddr[tap][mi] = (tap * 128 + wr * 64 + mi * 16 + (lane & 15)) * APAD + (lane >> 4) * 8;
    #pragma unroll
    for (int ni = 0; ni < 4; ++ni){
      int n_local = wc * 64 + ni * 16 + (lane & 15);
      int row = n_local >> 6, col = (n_local & 63) + tap;   // dw = tap-1 -> col = w+dw+1
      baddr[tap][ni] = (row * 68 + col) * BPAD + (lane >> 4) * 8;
    }
  }

  const unsigned short* ytb = ytr + (size_t)b * HH * WW * CIN;

  for (int dh = -1; dh <= 1; ++dh){
    const unsigned short* nwt = nw + ((size_t)((b * 9 + (dh + 1) * 3) * COUT + oc0)) * CIN;
    for (int icb = 0; icb < 8; ++icb){
      const int ic0 = icb * 32;
      __syncthreads();
      // stage y halo tile: 2 rows x 66 cols x 32 ic (16B chunks: 528)
      for (int idx = tid; idx < 528; idx += 256){
        int site = idx >> 2, ch = idx & 3;
        int row = site / 66, col = site - row * 66;
        int gh = h0 + row + dh, gw = col - 1;
        uint4 v = (uint4){0, 0, 0, 0};
        if ((unsigned)gh < 64u && (unsigned)gw < 64u)
          v = *(const uint4*)(ytb + ((size_t)(gh * 64 + gw)) * CIN + ic0 + ch * 8);
        *(uint4*)(&Yt[(row * 68 + col) * BPAD + ch * 8]) = v;
      }
      // stage A3: 3 taps x 128 oc x 32 ic (16B chunks: 1536 -> 6/thread)
      #pragma unroll
      for (int j = 0; j < 6; ++j){
        int idx = tid + j * 256;
        int tap = idx >> 9, r2 = idx & 511, row = r2 >> 2, ch = r2 & 3;
        uint4 v = *(const uint4*)(nwt + (size_t)tap * COUT * CIN + (size_t)row * CIN + ic0 + ch * 8);
        *(uint4*)(&Wa[(tap * 128 + row) * APAD + ch * 8]) = v;
      }
      __syncthreads();
      #pragma unroll
      for (int tap = 0; tap < 3; ++tap){
        short8 af[4], bfr[4];
        #pragma unroll
        for (int mi = 0; mi < 4; ++mi) af[mi] = *(const short8*)&Wa[aaddr[tap][mi]];
        #pragma unroll
        for (int ni = 0; ni < 4; ++ni) bfr[ni] = *(const short8*)&Yt[baddr[tap][ni]];
        #pragma unroll
        for (int mi = 0; mi < 4; ++mi)
          #pragma unroll
          for (int ni = 0; ni < 4; ++ni)
            acc[mi][ni] = __builtin_amdgcn_mfma_f32_16x16x32_bf16(af[mi], bfr[ni], acc[mi][ni], 0, 0, 0);
      }
    }
  }

  // epilogue: D layout col=lane&15 (hw), row=(lane>>4)*4+reg (oc)
  const int col_l = lane & 15, row_l = (lane >> 4) * 4;
  #pragma unroll
  for (int mi = 0; mi < 4; ++mi){
    #pragma unroll
    for (int r = 0; r < 4; ++r){
      const int ocl = wr * 64 + mi * 16 + row_l + r;
      const float bb = bsh[ocl];
      float* op = out + ((size_t)(b * COUT + oc0 + ocl)) * (HH * WW) + hw0 + wc * 64;
      #pragma unroll
      for (int ni = 0; ni < 4; ++ni)
        op[ni * 16 + col_l] = acc[mi][ni][r] + bb;
    }
  }
}

extern "C" void kernel_launch(void* const* d_in, const int* in_sizes, int n_in,
                              void* d_out, int out_size, void* d_ws, size_t ws_size,
                              hipStream_t stream){
  const float* y      = (const float*)d_in[0];
  const float* finger = (const float*)d_in[1];
  const float* ow     = (const float*)d_in[2];
  const float* wmask  = (const float*)d_in[3];
  const float* fwgt   = (const float*)d_in[4];
  const float* sw1    = (const float*)d_in[5];
  const float* sw2    = (const float*)d_in[6];
  const float* obias  = (const float*)d_in[7];
  const float* bmask  = (const float*)d_in[8];
  const float* fbias  = (const float*)d_in[9];
  const float* bw1    = (const float*)d_in[10];
  const float* bw2    = (const float*)d_in[11];
  float* out = (float*)d_out;
  float* ws  = (float*)d_ws;

  float* stat  = ws + OFF_STAT;
  float* bmean = ws + OFF_BMEAN;
  float* bstd  = ws + OFF_BSTD;
  float* ops   = ws + OFF_OPS;
  float* opq   = ws + OFF_OPQ;
  float* ps    = ws + OFF_PS;
  float* pq    = ws + OFF_PQ;
  float* h     = ws + OFF_H;
  float* style = ws + OFF_STYLE;
  float* nbias = ws + OFF_NBIAS;
  unsigned short* nw  = (unsigned short*)(ws + OFF_NW);
  unsigned short* ytr = (unsigned short*)(ws + OFF_YTR);

  k_ori_part<<<NPART, 256, 0, stream>>>(ow, ops, opq);
  k_ori_final<<<1, 64, 0, stream>>>(ops, opq, stat);
  k_style_h<<<(B * LAT + 255) / 256, 256, 0, stream>>>(finger, sw1, h);
  k_style<<<(B * 2 * WPS + 255) / 256, 256, 0, stream>>>(h, sw2, style);
  k_bias<<<B, COUT, 0, stream>>>(finger, bw1, bw2, fbias, bmask, obias, nbias);
  k_w1_part<<<dim3(NPART, B), 256, 0, stream>>>(ow, fwgt, wmask, style, ps, pq);
  k_w1_final<<<B, 64, 0, stream>>>(ps, pq, bmean, bstd);
  k_new_weight2<<<dim3(COUT, B), 256, 0, stream>>>(ow, fwgt, wmask, style, stat, bmean, bstd, nw);
  k_ytr<<<dim3(HH, B), 256, 0, stream>>>(y, ytr);
  k_conv_mfma3<<<dim3(32, 2, 16), 256, 0, stream>>>(ytr, nw, nbias, out);
}